// Round 5
// baseline (255.599 us; speedup 1.0000x reference)
//
#include <hip/hip_runtime.h>

#define N_NODES 100000
#define N_EDGES 1600000
#define IN_DIM  128
#define HIDDEN  128
#define OUT_DIM 64

#define NB_COARSE ((N_NODES + 255) / 256)   // 391 coarse buckets (256 nodes each)
#define EPB 4096                            // edges per block in k_part
#define NBLK_E ((N_EDGES + EPB - 1) / EPB)  // 391 blocks
#define CAP 5120                            // fixed bucket capacity (mean 4092 + 16 sigma)
#define PCAP 6912                           // padded bucket capacity (CAP + 256*7), mult of 8

typedef __attribute__((ext_vector_type(8))) short bf8_t;   // 8 x bf16 (4 VGPRs)
typedef __attribute__((ext_vector_type(4))) float f4_t;    // MFMA accumulator

__device__ __forceinline__ ushort f2b(float f) {           // fp32 -> bf16 RNE
    unsigned int u = __float_as_uint(f);
    u += 0x7fffu + ((u >> 16) & 1u);
    return (ushort)(u >> 16);
}
__device__ __forceinline__ float b2f_lo(unsigned int u) { return __uint_as_float(u << 16); }
__device__ __forceinline__ float b2f_hi(unsigned int u) { return __uint_as_float(u & 0xffff0000u); }

// ---------------- init: bucket cursors to fixed bases; zero h sentinel row ----------------

__global__ void k_zero(int* __restrict__ cursor, unsigned int* __restrict__ hz) {
    int t = threadIdx.x;
    if (t < NB_COARSE) cursor[t] = t * CAP;
    if (t >= NB_COARSE && t < NB_COARSE + 64)
        hz[(size_t)N_NODES * 64 + (t - NB_COARSE)] = 0u;   // bf16 zero row (256 B)
}

// ---------------- single-pass bucketed partition (fixed bases, no global scan) ----------------

__global__ __launch_bounds__(256) void k_part(const int* __restrict__ ei,
                                              int* __restrict__ cursor,
                                              unsigned int* __restrict__ part) {
    __shared__ int lh[NB_COARSE];     // local hist, then local cursor
    __shared__ int lbase[NB_COARSE];  // global base of this block's run per bucket
    int t = threadIdx.x;
    for (int i = t; i < NB_COARSE; i += 256) lh[i] = 0;
    __syncthreads();
    int e0 = blockIdx.x * EPB;
    int srcv[EPB / 256], dstv[EPB / 256];
    #pragma unroll
    for (int j = 0; j < EPB / 256; j++) {
        int e = e0 + j * 256 + t;
        if (e < N_EDGES) {
            srcv[j] = ei[e];
            dstv[j] = ei[N_EDGES + e];
            atomicAdd(&lh[dstv[j] >> 8], 1);
        } else dstv[j] = -1;
    }
    __syncthreads();
    for (int i = t; i < NB_COARSE; i += 256) {
        int c = lh[i];
        lbase[i] = (c > 0) ? atomicAdd(&cursor[i], c) : 0;
        lh[i] = 0;                    // becomes local cursor
    }
    __syncthreads();
    #pragma unroll
    for (int j = 0; j < EPB / 256; j++) {
        if (dstv[j] >= 0) {
            int b = dstv[j] >> 8;
            int pos = lbase[b] + atomicAdd(&lh[b], 1);
            part[pos] = ((unsigned int)(dstv[j] & 255) << 24) | (unsigned int)srcv[j];
        }
    }
}

// ------- per-bucket CSR finalize: padded per-node ranges (pad -> sentinel N_NODES) -------

__global__ __launch_bounds__(256) void k_csr(const unsigned int* __restrict__ part,
                                             const int* __restrict__ cursor,
                                             int* __restrict__ offs,
                                             int* __restrict__ pcnt,
                                             float* __restrict__ dinv,
                                             int* __restrict__ ssrc) {
    __shared__ int ldeg[256], lsc[256], lcur[256], sob[256];
    __shared__ unsigned int stage[CAP];
    int t = threadIdx.x;
    int b = blockIdx.x;
    int rbeg = b * CAP;
    int cnt = cursor[b] - rbeg;       // edges landed in this bucket
    int node0 = b << 8;
    ldeg[t] = 0;
    __syncthreads();
    for (int i = t; i < cnt; i += 256) {
        unsigned int u = part[rbeg + i];
        stage[i] = u;
        atomicAdd(&ldeg[u >> 24], 1);
    }
    __syncthreads();
    int v = ldeg[t];
    int pv = (v + 7) & ~7;            // padded to multiple of 8
    lsc[t] = pv;
    __syncthreads();
    for (int off = 1; off < 256; off <<= 1) {
        int add = (t >= off) ? lsc[t - off] : 0;
        __syncthreads();
        lsc[t] += add;
        __syncthreads();
    }
    int ob = b * PCAP + (lsc[t] - pv);   // padded output base for node (node0+t)
    sob[t] = ob;
    lcur[t] = 0;
    if (node0 + t < N_NODES) {
        offs[node0 + t] = ob;
        pcnt[node0 + t] = pv;
        dinv[node0 + t] = rsqrtf((float)(v + 1));   // +1: self-loop
    }
    __syncthreads();
    for (int i = t; i < cnt; i += 256) {
        unsigned int u = stage[i];
        int d = u >> 24;
        int pos = atomicAdd(&lcur[d], 1);
        ssrc[sob[d] + pos] = (int)(u & 0xFFFFFFu);
    }
    for (int i = v; i < pv; i++) ssrc[ob + i] = N_NODES;   // sentinel pads (zero row)
}

// ---------------- bf16 MFMA GEMM1: h = (x @ W1) * dinv[row], bf16 out ----------------

__global__ __launch_bounds__(256, 2) void k_mfma1(const float* __restrict__ A,
                                                  const float* __restrict__ W,
                                                  const float* __restrict__ dinv,
                                                  ushort* __restrict__ C, int M) {
    constexpr int BM = 128, KK = 128, PAD = 8, BN = 128, MF = 4, NF = 4;
    __shared__ ushort As[BM][KK + PAD];
    __shared__ ushort Bs[BN][KK + PAD];

    int tid = threadIdx.x;
    int row0 = blockIdx.x * BM;

    #pragma unroll
    for (int i = 0; i < 16; i++) {
        int li = tid + i * 256;
        int r = li >> 5, c4 = li & 31;
        int grow = row0 + r; if (grow > M - 1) grow = M - 1;
        float4 v = *(const float4*)(A + (size_t)grow * KK + c4 * 4);
        ushort4 o;
        o.x = f2b(v.x); o.y = f2b(v.y); o.z = f2b(v.z); o.w = f2b(v.w);
        *(ushort4*)&As[r][c4 * 4] = o;
    }
    #pragma unroll
    for (int i = 0; i < 16; i++) {
        int li = tid + i * 256;
        int k = li >> 5, n4 = li & 31;
        float4 v = *(const float4*)(W + (size_t)k * BN + n4 * 4);
        Bs[n4 * 4 + 0][k] = f2b(v.x);
        Bs[n4 * 4 + 1][k] = f2b(v.y);
        Bs[n4 * 4 + 2][k] = f2b(v.z);
        Bs[n4 * 4 + 3][k] = f2b(v.w);
    }
    __syncthreads();

    int wave = tid >> 6, lane = tid & 63;
    int lr = lane & 15, lq = lane >> 4;
    int wm0 = (wave & 1) * 64;
    int wn0 = (wave >> 1) * 64;

    f4_t acc[MF][NF];
    #pragma unroll
    for (int mi = 0; mi < MF; mi++)
        #pragma unroll
        for (int ni = 0; ni < NF; ni++) acc[mi][ni] = (f4_t){0.f, 0.f, 0.f, 0.f};

    #pragma unroll
    for (int kb = 0; kb < 4; kb++) {
        bf8_t af[MF], bfr[NF];
        #pragma unroll
        for (int mi = 0; mi < MF; mi++)
            af[mi] = *(const bf8_t*)&As[wm0 + mi * 16 + lr][kb * 32 + lq * 8];
        #pragma unroll
        for (int ni = 0; ni < NF; ni++)
            bfr[ni] = *(const bf8_t*)&Bs[wn0 + ni * 16 + lr][kb * 32 + lq * 8];
        #pragma unroll
        for (int mi = 0; mi < MF; mi++)
            #pragma unroll
            for (int ni = 0; ni < NF; ni++)
                acc[mi][ni] = __builtin_amdgcn_mfma_f32_16x16x32_bf16(
                    af[mi], bfr[ni], acc[mi][ni], 0, 0, 0);
    }

    #pragma unroll
    for (int mi = 0; mi < MF; mi++) {
        #pragma unroll
        for (int r = 0; r < 4; r++) {
            int row = row0 + wm0 + mi * 16 + lq * 4 + r;
            if (row < M) {
                float dv = dinv[row];
                #pragma unroll
                for (int ni = 0; ni < NF; ni++)
                    C[(size_t)row * BN + wn0 + ni * 16 + lr] = f2b(acc[mi][ni][r] * dv);
            }
        }
    }
}

// ------- fused aggregation + GEMM2: out = relu(agg) @ W2 + b2 -------
// Phase A: 8 waves aggregate 128 node rows (h2, bf16) into LDS A-tile.
// Phase B: MFMA 128x64x128 with W2 staged bf16, fp32 epilogue + b2.

__global__ __launch_bounds__(512, 6) void k_aggmm(const ushort* __restrict__ h,
                                                  const int* __restrict__ offs,
                                                  const int* __restrict__ pcnt,
                                                  const int* __restrict__ ssrc,
                                                  const float* __restrict__ dinv,
                                                  const float* __restrict__ b1,
                                                  const float* __restrict__ W2,
                                                  const float* __restrict__ b2,
                                                  float* __restrict__ out, int M) {
    constexpr int BM = 128, KK = 128, PAD = 8, BN = 64;
    __shared__ ushort As[BM][KK + PAD];   // aggregated h2 tile (bf16)
    __shared__ ushort Bs[BN][KK + PAD];   // W2, n-major

    int tid = threadIdx.x;
    int wave = tid >> 6, lane = tid & 63;
    int row0 = blockIdx.x * BM;

    // stage W2 (128x64 fp32 -> Bs[n][k] bf16)
    #pragma unroll
    for (int i = 0; i < 4; i++) {
        int li = tid + i * 512;           // 2048 float4 loads
        int k = li >> 4, n4 = li & 15;
        float4 v = *(const float4*)(W2 + (size_t)k * BN + n4 * 4);
        Bs[n4 * 4 + 0][k] = f2b(v.x);
        Bs[n4 * 4 + 1][k] = f2b(v.y);
        Bs[n4 * 4 + 2][k] = f2b(v.z);
        Bs[n4 * 4 + 3][k] = f2b(v.w);
    }

    // Phase A: aggregate 16 nodes per wave into As
    const unsigned int* hp = (const unsigned int*)h;  // 2 bf16 per uint, 64 uints/row
    float2 bb = ((const float2*)b1)[lane];
    #pragma unroll 1
    for (int nn = 0; nn < 16; nn++) {
        int r = wave * 16 + nn;
        int n = row0 + r;
        if (n >= M) break;
        int e0 = offs[n];
        int iters = pcnt[n] >> 3;
        const uint4* ip = (const uint4*)(ssrc + e0);  // 32B-aligned

        float2 a0 = {0.f, 0.f}, a1 = {0.f, 0.f}, a2 = {0.f, 0.f}, a3 = {0.f, 0.f};
        uint4 i0, i1;
        if (iters > 0) { i0 = ip[0]; i1 = ip[1]; }
        for (int it = 0; it < iters; it++) {
            uint4 nx0 = i0, nx1 = i1;
            if (it + 1 < iters) { nx0 = ip[(it + 1) * 2]; nx1 = ip[(it + 1) * 2 + 1]; }
            unsigned int u0 = hp[i0.x * 64 + lane];
            unsigned int u1 = hp[i0.y * 64 + lane];
            unsigned int u2 = hp[i0.z * 64 + lane];
            unsigned int u3 = hp[i0.w * 64 + lane];
            unsigned int u4 = hp[i1.x * 64 + lane];
            unsigned int u5 = hp[i1.y * 64 + lane];
            unsigned int u6 = hp[i1.z * 64 + lane];
            unsigned int u7 = hp[i1.w * 64 + lane];
            a0.x += b2f_lo(u0); a0.y += b2f_hi(u0);
            a1.x += b2f_lo(u1); a1.y += b2f_hi(u1);
            a2.x += b2f_lo(u2); a2.y += b2f_hi(u2);
            a3.x += b2f_lo(u3); a3.y += b2f_hi(u3);
            a0.x += b2f_lo(u4); a0.y += b2f_hi(u4);
            a1.x += b2f_lo(u5); a1.y += b2f_hi(u5);
            a2.x += b2f_lo(u6); a2.y += b2f_hi(u6);
            a3.x += b2f_lo(u7); a3.y += b2f_hi(u7);
            i0 = nx0; i1 = nx1;
        }
        unsigned int us = hp[(size_t)n * 64 + lane];  // self term: hs[n]*dinv[n]
        float dn = dinv[n];
        float rx = (a0.x + a1.x + a2.x + a3.x + b2f_lo(us)) * dn + bb.x;
        float ry = (a0.y + a1.y + a2.y + a3.y + b2f_hi(us)) * dn + bb.y;
        rx = rx > 0.f ? rx : 0.f;
        ry = ry > 0.f ? ry : 0.f;
        unsigned int o = ((unsigned int)f2b(ry) << 16) | (unsigned int)f2b(rx);
        *(unsigned int*)&As[r][lane * 2] = o;
    }
    __syncthreads();

    // Phase B: MFMA — wave w covers rows [w*16, w*16+16), all 64 cols
    int lr = lane & 15, lq = lane >> 4;
    f4_t acc[4];
    #pragma unroll
    for (int ni = 0; ni < 4; ni++) acc[ni] = (f4_t){0.f, 0.f, 0.f, 0.f};
    #pragma unroll
    for (int kb = 0; kb < 4; kb++) {
        bf8_t af = *(const bf8_t*)&As[wave * 16 + lr][kb * 32 + lq * 8];
        #pragma unroll
        for (int ni = 0; ni < 4; ni++) {
            bf8_t bf = *(const bf8_t*)&Bs[ni * 16 + lr][kb * 32 + lq * 8];
            acc[ni] = __builtin_amdgcn_mfma_f32_16x16x32_bf16(af, bf, acc[ni], 0, 0, 0);
        }
    }
    #pragma unroll
    for (int r = 0; r < 4; r++) {
        int row = row0 + wave * 16 + lq * 4 + r;
        if (row < M) {
            #pragma unroll
            for (int ni = 0; ni < 4; ni++) {
                int col = ni * 16 + lr;
                out[(size_t)row * BN + col] = acc[ni][r] + b2[col];
            }
        }
    }
}

// ---------------- launch ----------------

extern "C" void kernel_launch(void* const* d_in, const int* in_sizes, int n_in,
                              void* d_out, int out_size, void* d_ws, size_t ws_size,
                              hipStream_t stream) {
    const float* x  = (const float*)d_in[0];
    const float* W1 = (const float*)d_in[1];
    const float* b1 = (const float*)d_in[2];
    const float* W2 = (const float*)d_in[3];
    const float* b2 = (const float*)d_in[4];
    const int*   ei = (const int*)d_in[5];
    float* out = (float*)d_out;

    char* w = (char*)d_ws;
    size_t off = 0;
    auto alloc = [&](size_t bytes) -> void* {
        void* p = w + off;
        off += (bytes + 255) & ~(size_t)255;
        return p;
    };
    ushort* h      = (ushort*)alloc((size_t)(N_NODES + 1) * HIDDEN * 2);  // +1 sentinel row
    float* dinv    = (float*)alloc((size_t)N_NODES * 4);
    int*   offs    = (int*)alloc((size_t)N_NODES * 4);
    int*   pcnt    = (int*)alloc((size_t)N_NODES * 4);
    int*   ssrc    = (int*)alloc((size_t)NB_COARSE * PCAP * 4);
    unsigned int* part = (unsigned int*)alloc((size_t)NB_COARSE * CAP * 4);
    int*   cursor  = (int*)alloc((size_t)NB_COARSE * 4);

    k_zero<<<1, 512, 0, stream>>>(cursor, (unsigned int*)h);
    k_part<<<NBLK_E, 256, 0, stream>>>(ei, cursor, part);
    k_csr<<<NB_COARSE, 256, 0, stream>>>(part, cursor, offs, pcnt, dinv, ssrc);

    k_mfma1<<<(N_NODES + 127) / 128, 256, 0, stream>>>(x, W1, dinv, h, N_NODES);
    k_aggmm<<<(N_NODES + 127) / 128, 512, 0, stream>>>(h, offs, pcnt, ssrc, dinv,
                                                       b1, W2, b2, out, N_NODES);
}

// Round 6
// 238.578 us; speedup vs baseline: 1.0713x; 1.0713x over previous
//
#include <hip/hip_runtime.h>

#define N_NODES 100000
#define N_EDGES 1600000
#define IN_DIM  128
#define HIDDEN  128
#define OUT_DIM 64

#define NB_COARSE ((N_NODES + 255) / 256)   // 391 coarse buckets (256 nodes each)
#define EPB 4096                            // edges per block in k_part
#define NBLK_E ((N_EDGES + EPB - 1) / EPB)  // 391 blocks
#define CAP 5120                            // fixed bucket capacity (mean 4092 + 16 sigma)
#define PCAP 6912                           // padded bucket capacity (CAP + 256*7), mult of 8

typedef __attribute__((ext_vector_type(8))) short bf8_t;   // 8 x bf16 (4 VGPRs)
typedef __attribute__((ext_vector_type(4))) float f4_t;    // MFMA accumulator

__device__ __forceinline__ ushort f2b(float f) {           // fp32 -> bf16 RNE
    unsigned int u = __float_as_uint(f);
    u += 0x7fffu + ((u >> 16) & 1u);
    return (ushort)(u >> 16);
}
__device__ __forceinline__ float b2f_lo(unsigned int u) { return __uint_as_float(u << 16); }
__device__ __forceinline__ float b2f_hi(unsigned int u) { return __uint_as_float(u & 0xffff0000u); }

// ---------------- init: bucket cursors to fixed bases; zero h sentinel row ----------------

__global__ void k_zero(int* __restrict__ cursor, unsigned int* __restrict__ hz) {
    int t = threadIdx.x;
    if (t < NB_COARSE) cursor[t] = t * CAP;
    if (t >= NB_COARSE && t < NB_COARSE + 64)
        hz[(size_t)N_NODES * 64 + (t - NB_COARSE)] = 0u;   // bf16 zero row (256 B)
}

// ---------------- single-pass bucketed partition (fixed bases, no global scan) ----------------

__global__ __launch_bounds__(256) void k_part(const int* __restrict__ ei,
                                              int* __restrict__ cursor,
                                              unsigned int* __restrict__ part) {
    __shared__ int lh[NB_COARSE];     // local hist, then local cursor
    __shared__ int lbase[NB_COARSE];  // global base of this block's run per bucket
    int t = threadIdx.x;
    for (int i = t; i < NB_COARSE; i += 256) lh[i] = 0;
    __syncthreads();
    int e0 = blockIdx.x * EPB;
    int srcv[EPB / 256], dstv[EPB / 256];
    #pragma unroll
    for (int j = 0; j < EPB / 256; j++) {
        int e = e0 + j * 256 + t;
        if (e < N_EDGES) {
            srcv[j] = ei[e];
            dstv[j] = ei[N_EDGES + e];
            atomicAdd(&lh[dstv[j] >> 8], 1);
        } else dstv[j] = -1;
    }
    __syncthreads();
    for (int i = t; i < NB_COARSE; i += 256) {
        int c = lh[i];
        lbase[i] = (c > 0) ? atomicAdd(&cursor[i], c) : 0;
        lh[i] = 0;                    // becomes local cursor
    }
    __syncthreads();
    #pragma unroll
    for (int j = 0; j < EPB / 256; j++) {
        if (dstv[j] >= 0) {
            int b = dstv[j] >> 8;
            int pos = lbase[b] + atomicAdd(&lh[b], 1);
            part[pos] = ((unsigned int)(dstv[j] & 255) << 24) | (unsigned int)srcv[j];
        }
    }
}

// ------- per-bucket CSR finalize: padded per-node ranges (pad -> sentinel N_NODES) -------

__global__ __launch_bounds__(256) void k_csr(const unsigned int* __restrict__ part,
                                             const int* __restrict__ cursor,
                                             int* __restrict__ offs,
                                             int* __restrict__ pcnt,
                                             float* __restrict__ dinv,
                                             int* __restrict__ ssrc) {
    __shared__ int ldeg[256], lsc[256], lcur[256], sob[256];
    __shared__ unsigned int stage[CAP];
    int t = threadIdx.x;
    int b = blockIdx.x;
    int rbeg = b * CAP;
    int cnt = cursor[b] - rbeg;       // edges landed in this bucket
    int node0 = b << 8;
    ldeg[t] = 0;
    __syncthreads();
    for (int i = t; i < cnt; i += 256) {
        unsigned int u = part[rbeg + i];
        stage[i] = u;
        atomicAdd(&ldeg[u >> 24], 1);
    }
    __syncthreads();
    int v = ldeg[t];
    int pv = (v + 7) & ~7;            // padded to multiple of 8
    lsc[t] = pv;
    __syncthreads();
    for (int off = 1; off < 256; off <<= 1) {
        int add = (t >= off) ? lsc[t - off] : 0;
        __syncthreads();
        lsc[t] += add;
        __syncthreads();
    }
    int ob = b * PCAP + (lsc[t] - pv);   // padded output base for node (node0+t)
    sob[t] = ob;
    lcur[t] = 0;
    if (node0 + t < N_NODES) {
        offs[node0 + t] = ob;
        pcnt[node0 + t] = pv;
        dinv[node0 + t] = rsqrtf((float)(v + 1));   // +1: self-loop
    }
    __syncthreads();
    for (int i = t; i < cnt; i += 256) {
        unsigned int u = stage[i];
        int d = u >> 24;
        int pos = atomicAdd(&lcur[d], 1);
        ssrc[sob[d] + pos] = (int)(u & 0xFFFFFFu);
    }
    for (int i = v; i < pv; i++) ssrc[ob + i] = N_NODES;   // sentinel pads (zero row)
}

// ---------------- bf16 MFMA GEMM1: h = (x @ W1) * dinv[row], bf16 out ----------------

__global__ __launch_bounds__(256, 2) void k_mfma1(const float* __restrict__ A,
                                                  const float* __restrict__ W,
                                                  const float* __restrict__ dinv,
                                                  ushort* __restrict__ C, int M) {
    constexpr int BM = 128, KK = 128, PAD = 8, BN = 128, MF = 4, NF = 4;
    __shared__ ushort As[BM][KK + PAD];
    __shared__ ushort Bs[BN][KK + PAD];

    int tid = threadIdx.x;
    int row0 = blockIdx.x * BM;

    #pragma unroll
    for (int i = 0; i < 16; i++) {
        int li = tid + i * 256;
        int r = li >> 5, c4 = li & 31;
        int grow = row0 + r; if (grow > M - 1) grow = M - 1;
        float4 v = *(const float4*)(A + (size_t)grow * KK + c4 * 4);
        ushort4 o;
        o.x = f2b(v.x); o.y = f2b(v.y); o.z = f2b(v.z); o.w = f2b(v.w);
        *(ushort4*)&As[r][c4 * 4] = o;
    }
    #pragma unroll
    for (int i = 0; i < 16; i++) {
        int li = tid + i * 256;
        int k = li >> 5, n4 = li & 31;
        float4 v = *(const float4*)(W + (size_t)k * BN + n4 * 4);
        Bs[n4 * 4 + 0][k] = f2b(v.x);
        Bs[n4 * 4 + 1][k] = f2b(v.y);
        Bs[n4 * 4 + 2][k] = f2b(v.z);
        Bs[n4 * 4 + 3][k] = f2b(v.w);
    }
    __syncthreads();

    int wave = tid >> 6, lane = tid & 63;
    int lr = lane & 15, lq = lane >> 4;
    int wm0 = (wave & 1) * 64;
    int wn0 = (wave >> 1) * 64;

    f4_t acc[MF][NF];
    #pragma unroll
    for (int mi = 0; mi < MF; mi++)
        #pragma unroll
        for (int ni = 0; ni < NF; ni++) acc[mi][ni] = (f4_t){0.f, 0.f, 0.f, 0.f};

    #pragma unroll
    for (int kb = 0; kb < 4; kb++) {
        bf8_t af[MF], bfr[NF];
        #pragma unroll
        for (int mi = 0; mi < MF; mi++)
            af[mi] = *(const bf8_t*)&As[wm0 + mi * 16 + lr][kb * 32 + lq * 8];
        #pragma unroll
        for (int ni = 0; ni < NF; ni++)
            bfr[ni] = *(const bf8_t*)&Bs[wn0 + ni * 16 + lr][kb * 32 + lq * 8];
        #pragma unroll
        for (int mi = 0; mi < MF; mi++)
            #pragma unroll
            for (int ni = 0; ni < NF; ni++)
                acc[mi][ni] = __builtin_amdgcn_mfma_f32_16x16x32_bf16(
                    af[mi], bfr[ni], acc[mi][ni], 0, 0, 0);
    }

    #pragma unroll
    for (int mi = 0; mi < MF; mi++) {
        #pragma unroll
        for (int r = 0; r < 4; r++) {
            int row = row0 + wm0 + mi * 16 + lq * 4 + r;
            if (row < M) {
                float dv = dinv[row];
                #pragma unroll
                for (int ni = 0; ni < NF; ni++)
                    C[(size_t)row * BN + wn0 + ni * 16 + lr] = f2b(acc[mi][ni][r] * dv);
            }
        }
    }
}

// ---------------- bf16 MFMA GEMM2: out = h2 @ W2 + b2 (fp32 out) ----------------

__global__ __launch_bounds__(256, 2) void k_mfma2(const ushort* __restrict__ A,
                                                  const float* __restrict__ W,
                                                  const float* __restrict__ bias,
                                                  float* __restrict__ C, int M) {
    constexpr int BM = 128, KK = 128, PAD = 8, BN = 64, MF = 2, NF = 4;
    __shared__ ushort As[BM][KK + PAD];
    __shared__ ushort Bs[BN][KK + PAD];

    int tid = threadIdx.x;
    int row0 = blockIdx.x * BM;

    #pragma unroll
    for (int i = 0; i < 8; i++) {
        int li = tid + i * 256;           // 128*16 uint4 loads
        int r = li >> 4, c8 = li & 15;
        int grow = row0 + r; if (grow > M - 1) grow = M - 1;
        uint4 v = *(const uint4*)(A + (size_t)grow * KK + c8 * 8);
        *(uint4*)&As[r][c8 * 8] = v;
    }
    #pragma unroll
    for (int i = 0; i < 8; i++) {
        int li = tid + i * 256;           // 128*16 float4 loads
        int k = li >> 4, n4 = li & 15;
        float4 v = *(const float4*)(W + (size_t)k * BN + n4 * 4);
        Bs[n4 * 4 + 0][k] = f2b(v.x);
        Bs[n4 * 4 + 1][k] = f2b(v.y);
        Bs[n4 * 4 + 2][k] = f2b(v.z);
        Bs[n4 * 4 + 3][k] = f2b(v.w);
    }
    __syncthreads();

    int wave = tid >> 6, lane = tid & 63;
    int lr = lane & 15, lq = lane >> 4;
    int wm0 = wave * 32;

    f4_t acc[MF][NF];
    #pragma unroll
    for (int mi = 0; mi < MF; mi++)
        #pragma unroll
        for (int ni = 0; ni < NF; ni++) acc[mi][ni] = (f4_t){0.f, 0.f, 0.f, 0.f};

    #pragma unroll
    for (int kb = 0; kb < 4; kb++) {
        bf8_t af[MF], bfr[NF];
        #pragma unroll
        for (int mi = 0; mi < MF; mi++)
            af[mi] = *(const bf8_t*)&As[wm0 + mi * 16 + lr][kb * 32 + lq * 8];
        #pragma unroll
        for (int ni = 0; ni < NF; ni++)
            bfr[ni] = *(const bf8_t*)&Bs[ni * 16 + lr][kb * 32 + lq * 8];
        #pragma unroll
        for (int mi = 0; mi < MF; mi++)
            #pragma unroll
            for (int ni = 0; ni < NF; ni++)
                acc[mi][ni] = __builtin_amdgcn_mfma_f32_16x16x32_bf16(
                    af[mi], bfr[ni], acc[mi][ni], 0, 0, 0);
    }

    #pragma unroll
    for (int mi = 0; mi < MF; mi++) {
        #pragma unroll
        for (int r = 0; r < 4; r++) {
            int row = row0 + wm0 + mi * 16 + lq * 4 + r;
            if (row < M) {
                #pragma unroll
                for (int ni = 0; ni < NF; ni++) {
                    int col = ni * 16 + lr;
                    C[(size_t)row * BN + col] = acc[mi][ni][r] + bias[col];
                }
            }
        }
    }
}

// -------- aggregation: h2[n] = bf16(relu(b1 + dinv[n]*(hs[n] + sum_s hs[s]))) --------
// One wave per node. 4 lane-groups of 16; each lane loads uint4 (16 B), so one
// dwordx4 gather instruction covers 4 edge rows (4x fewer address-processing slots).
// Edge lists padded to multiples of 8 with sentinel N_NODES (zero row).

__global__ __launch_bounds__(256) void k_agg(const ushort* __restrict__ h,
                                             const int* __restrict__ offs,
                                             const int* __restrict__ pcnt,
                                             const int* __restrict__ ssrc,
                                             const float* __restrict__ dinv,
                                             const float* __restrict__ b1,
                                             ushort* __restrict__ h2) {
    int wave = threadIdx.x >> 6;
    int lane = threadIdx.x & 63;
    int n = blockIdx.x * 4 + wave;
    if (n >= N_NODES) return;
    int g  = lane >> 4;       // edge group 0..3
    int gl = lane & 15;       // 16 lanes cover one 256 B row

    const uint4* hp4 = (const uint4*)h;   // 16 uint4 per row
    int e0 = offs[n];
    int iters = pcnt[n] >> 3;             // 8 edges per iteration
    const uint4* ip = (const uint4*)(ssrc + e0);   // 32B-aligned

    float ac0 = 0.f, ac1 = 0.f, ac2 = 0.f, ac3 = 0.f;
    float ac4 = 0.f, ac5 = 0.f, ac6 = 0.f, ac7 = 0.f;

    uint4 i0 = ip[0], i1 = ip[1];         // safe: pads exist; unused if iters==0
    for (int it = 0; it < iters; it++) {
        uint4 nx0 = ip[2 * it + 2];       // prefetch (over-read lands in ws, never used)
        uint4 nx1 = ip[2 * it + 3];
        unsigned int s0 = (g & 2) ? ((g & 1) ? i0.w : i0.z) : ((g & 1) ? i0.y : i0.x);
        unsigned int s1 = (g & 2) ? ((g & 1) ? i1.w : i1.z) : ((g & 1) ? i1.y : i1.x);
        uint4 ua = hp4[(size_t)s0 * 16 + gl];
        uint4 ub = hp4[(size_t)s1 * 16 + gl];
        ac0 += b2f_lo(ua.x); ac1 += b2f_hi(ua.x);
        ac2 += b2f_lo(ua.y); ac3 += b2f_hi(ua.y);
        ac4 += b2f_lo(ua.z); ac5 += b2f_hi(ua.z);
        ac6 += b2f_lo(ua.w); ac7 += b2f_hi(ua.w);
        ac0 += b2f_lo(ub.x); ac1 += b2f_hi(ub.x);
        ac2 += b2f_lo(ub.y); ac3 += b2f_hi(ub.y);
        ac4 += b2f_lo(ub.z); ac5 += b2f_hi(ub.z);
        ac6 += b2f_lo(ub.w); ac7 += b2f_hi(ub.w);
        i0 = nx0; i1 = nx1;
    }
    // cross-group reduction (lane^16, lane^32)
    ac0 += __shfl_xor(ac0, 16); ac1 += __shfl_xor(ac1, 16);
    ac2 += __shfl_xor(ac2, 16); ac3 += __shfl_xor(ac3, 16);
    ac4 += __shfl_xor(ac4, 16); ac5 += __shfl_xor(ac5, 16);
    ac6 += __shfl_xor(ac6, 16); ac7 += __shfl_xor(ac7, 16);
    ac0 += __shfl_xor(ac0, 32); ac1 += __shfl_xor(ac1, 32);
    ac2 += __shfl_xor(ac2, 32); ac3 += __shfl_xor(ac3, 32);
    ac4 += __shfl_xor(ac4, 32); ac5 += __shfl_xor(ac5, 32);
    ac6 += __shfl_xor(ac6, 32); ac7 += __shfl_xor(ac7, 32);

    // epilogue: self term + scale + bias + relu, pack, store (group 0 only)
    uint4 us = hp4[(size_t)n * 16 + gl];      // hs[n] (already *dinv[n])
    float dn = dinv[n];
    float4 ba = *(const float4*)(b1 + gl * 8);
    float4 bc = *(const float4*)(b1 + gl * 8 + 4);
    float r0 = (ac0 + b2f_lo(us.x)) * dn + ba.x;
    float r1 = (ac1 + b2f_hi(us.x)) * dn + ba.y;
    float r2 = (ac2 + b2f_lo(us.y)) * dn + ba.z;
    float r3 = (ac3 + b2f_hi(us.y)) * dn + ba.w;
    float r4 = (ac4 + b2f_lo(us.z)) * dn + bc.x;
    float r5 = (ac5 + b2f_hi(us.z)) * dn + bc.y;
    float r6 = (ac6 + b2f_lo(us.w)) * dn + bc.z;
    float r7 = (ac7 + b2f_hi(us.w)) * dn + bc.w;
    r0 = r0 > 0.f ? r0 : 0.f;  r1 = r1 > 0.f ? r1 : 0.f;
    r2 = r2 > 0.f ? r2 : 0.f;  r3 = r3 > 0.f ? r3 : 0.f;
    r4 = r4 > 0.f ? r4 : 0.f;  r5 = r5 > 0.f ? r5 : 0.f;
    r6 = r6 > 0.f ? r6 : 0.f;  r7 = r7 > 0.f ? r7 : 0.f;
    if (g == 0) {
        uint4 o;
        o.x = ((unsigned int)f2b(r1) << 16) | (unsigned int)f2b(r0);
        o.y = ((unsigned int)f2b(r3) << 16) | (unsigned int)f2b(r2);
        o.z = ((unsigned int)f2b(r5) << 16) | (unsigned int)f2b(r4);
        o.w = ((unsigned int)f2b(r7) << 16) | (unsigned int)f2b(r6);
        ((uint4*)h2)[(size_t)n * 16 + gl] = o;
    }
}

// ---------------- launch ----------------

extern "C" void kernel_launch(void* const* d_in, const int* in_sizes, int n_in,
                              void* d_out, int out_size, void* d_ws, size_t ws_size,
                              hipStream_t stream) {
    const float* x  = (const float*)d_in[0];
    const float* W1 = (const float*)d_in[1];
    const float* b1 = (const float*)d_in[2];
    const float* W2 = (const float*)d_in[3];
    const float* b2 = (const float*)d_in[4];
    const int*   ei = (const int*)d_in[5];
    float* out = (float*)d_out;

    char* w = (char*)d_ws;
    size_t off = 0;
    auto alloc = [&](size_t bytes) -> void* {
        void* p = w + off;
        off += (bytes + 255) & ~(size_t)255;
        return p;
    };
    ushort* h      = (ushort*)alloc((size_t)(N_NODES + 1) * HIDDEN * 2);  // +1 sentinel row
    ushort* h2     = (ushort*)alloc((size_t)N_NODES * HIDDEN * 2);
    float* dinv    = (float*)alloc((size_t)N_NODES * 4);
    int*   offs    = (int*)alloc((size_t)N_NODES * 4);
    int*   pcnt    = (int*)alloc((size_t)N_NODES * 4);
    int*   ssrc    = (int*)alloc((size_t)NB_COARSE * PCAP * 4);
    unsigned int* part = (unsigned int*)alloc((size_t)NB_COARSE * CAP * 4);
    int*   cursor  = (int*)alloc((size_t)NB_COARSE * 4);

    k_zero<<<1, 512, 0, stream>>>(cursor, (unsigned int*)h);
    k_part<<<NBLK_E, 256, 0, stream>>>(ei, cursor, part);
    k_csr<<<NB_COARSE, 256, 0, stream>>>(part, cursor, offs, pcnt, dinv, ssrc);

    k_mfma1<<<(N_NODES + 127) / 128, 256, 0, stream>>>(x, W1, dinv, h, N_NODES);
    k_agg<<<(N_NODES + 3) / 4, 256, 0, stream>>>(h, offs, pcnt, ssrc, dinv, b1, h2);
    k_mfma2<<<(N_NODES + 127) / 128, 256, 0, stream>>>(h2, W2, b2, out, N_NODES);
}